// Round 5
// baseline (245.950 us; speedup 1.0000x reference)
//
#include <hip/hip_runtime.h>

#define LAMBDA_COORD 5.0f
#define LAMBDA_NOOBJ 0.5f
#define WH_EPS 1e-6f
#define IOU_EPS 1e-6f

__device__ __forceinline__ float sq(float x) { return x * x; }

__device__ __forceinline__ float iou_yolo(float a0, float a1, float a2, float a3,
                                          float b0, float b1, float b2, float b3) {
    float ax1 = a0 - a2 * 0.5f, ay1 = a1 - a3 * 0.5f;
    float ax2 = a0 + a2 * 0.5f, ay2 = a1 + a3 * 0.5f;
    float bx1 = b0 - b2 * 0.5f, by1 = b1 - b3 * 0.5f;
    float bx2 = b0 + b2 * 0.5f, by2 = b1 + b3 * 0.5f;
    float iw = fmaxf(fminf(ax2, bx2) - fmaxf(ax1, bx1), 0.0f);
    float ih = fmaxf(fminf(ay2, by2) - fmaxf(ay1, by1), 0.0f);
    float inter = iw * ih;
    float area_a = fabsf((ax2 - ax1) * (ay2 - ay1));
    float area_b = fabsf((bx2 - bx1) * (by2 - by1));
    return inter / (area_a + area_b - inter + IOU_EPS);
}

// All terms for one cell given its 15 scalars (t side), 10 box/conf preds,
// and the precomputed class SSE.
__device__ __forceinline__ float cell_terms(
    float b0, float b1, float b2, float b3, float t4,
    float p0, float p1, float p2, float p3, float p4,
    float p5, float p6, float p7, float p8, float p9, float cls) {
    float iou1 = iou_yolo(b0, b1, b2, b3, p0, p1, p2, p3);
    float iou2 = iou_yolo(b0, b1, b2, b3, p5, p6, p7, p8);
    bool use1 = iou1 > iou2;

    float bh0 = use1 ? p0 : p5;
    float bh1 = use1 ? p1 : p6;
    float bh2 = use1 ? p2 : p7;
    float bh3 = use1 ? p3 : p8;
    float conf_c = use1 ? p4 : p9;
    float conf_o = use1 ? p9 : p4;

    float dx = b0 - bh0, dy = b1 - bh1;
    float xy = LAMBDA_COORD * (dx * dx + dy * dy);

    float sw = sqrtf(b2) - sqrtf(fabsf(bh2 + WH_EPS));
    float sh = sqrtf(b3) - sqrtf(fabsf(bh3 + WH_EPS));
    float wh = LAMBDA_COORD * (sw * sw + sh * sh);

    float dc = t4 - conf_c;
    float obj_terms = xy + wh + dc * dc + LAMBDA_NOOBJ * conf_o * conf_o + cls;

    float d4 = t4 - p4, d9 = t4 - p9;
    float noobj_terms = LAMBDA_NOOBJ * (d4 * d4 + d9 * d9);

    return (t4 == 1.0f) ? obj_terms : noobj_terms;
}

// One thread per cell PAIR (240 B, 16B-aligned -> float4). ALL loads issued
// before any use; __launch_bounds__(256,1) unlocks the VGPR budget (~150
// landing+addr regs) so the compiler does NOT batch-serialize the loads.
// No LDS staging, no mid-kernel barrier -> continuous issue, ~370 KB in
// flight per CU at 12 waves/CU. T-float4 #9 (floats 36-39 = y_trues fields
// 5-9 of the odd cell) is never read by the reference -> skipped.
__global__ __launch_bounds__(256, 1) void yolo_loss_kernel(
    const float* __restrict__ t_g, const float* __restrict__ p_g,
    float* __restrict__ out, int n_pairs, float inv_batch) {
    const int pp = blockIdx.x * blockDim.x + threadIdx.x;

    float v = 0.0f;
    if (pp < n_pairs) {
        const float4* tv = (const float4*)t_g + (size_t)pp * 15;
        const float4* pv = (const float4*)p_g + (size_t)pp * 15;

        float4 T[15], P[15];
#pragma unroll
        for (int i = 0; i < 15; ++i) P[i] = pv[i];
#pragma unroll
        for (int i = 0; i < 15; ++i)
            if (i != 9) T[i] = tv[i];          // floats 36-39 never used
        T[9] = make_float4(0.f, 0.f, 0.f, 0.f);

        // ---- cell A: floats 0..29 ----
        float clsA = sq(T[2].z - P[2].z) + sq(T[2].w - P[2].w);
#pragma unroll
        for (int i = 3; i < 7; ++i) {
            clsA += sq(T[i].x - P[i].x) + sq(T[i].y - P[i].y) +
                    sq(T[i].z - P[i].z) + sq(T[i].w - P[i].w);
        }
        clsA += sq(T[7].x - P[7].x) + sq(T[7].y - P[7].y);

        float vA = cell_terms(T[0].x, T[0].y, T[0].z, T[0].w, T[1].x,
                              P[0].x, P[0].y, P[0].z, P[0].w, P[1].x,
                              P[1].y, P[1].z, P[1].w, P[2].x, P[2].y, clsA);

        // ---- cell B: floats 30..59 ----
        float clsB = 0.0f;
#pragma unroll
        for (int i = 10; i < 15; ++i) {
            clsB += sq(T[i].x - P[i].x) + sq(T[i].y - P[i].y) +
                    sq(T[i].z - P[i].z) + sq(T[i].w - P[i].w);
        }

        float vB = cell_terms(T[7].z, T[7].w, T[8].x, T[8].y, T[8].z,
                              P[7].z, P[7].w, P[8].x, P[8].y, P[8].z,
                              P[8].w, P[9].x, P[9].y, P[9].z, P[9].w, clsB);

        v = vA + vB;
    }

    // wave64 reduction -> per-wave LDS -> one atomic per block
#pragma unroll
    for (int off = 32; off > 0; off >>= 1)
        v += __shfl_down(v, off, 64);

    __shared__ float swave[4];
    const int lane = threadIdx.x & 63;
    const int wid = threadIdx.x >> 6;
    if (lane == 0) swave[wid] = v;
    __syncthreads();
    if (threadIdx.x == 0) {
        float s = swave[0] + swave[1] + swave[2] + swave[3];
        atomicAdd(out, s * inv_batch);
    }
}

extern "C" void kernel_launch(void* const* d_in, const int* in_sizes, int n_in,
                              void* d_out, int out_size, void* d_ws, size_t ws_size,
                              hipStream_t stream) {
    const float* t = (const float*)d_in[0];  // y_trues
    const float* p = (const float*)d_in[1];  // y_preds
    float* out = (float*)d_out;

    const int total = in_sizes[0];       // 24,084,480
    const int cells = total / 30;        // 802,816
    const int pairs = cells / 2;         // 401,408
    const int batch = cells / 49;        // 16,384
    const float inv_batch = 1.0f / (float)batch;

    // d_out is poisoned (0xAA) before every replay — zero it on-stream.
    hipMemsetAsync(out, 0, sizeof(float), stream);

    const int block = 256;
    const int grid = (pairs + block - 1) / block;  // 1568
    yolo_loss_kernel<<<grid, block, 0, stream>>>(t, p, out, pairs, inv_batch);
}

// Round 6
// 212.895 us; speedup vs baseline: 1.1553x; 1.1553x over previous
//
#include <hip/hip_runtime.h>

#define LAMBDA_COORD 5.0f
#define LAMBDA_NOOBJ 0.5f
#define WH_EPS 1e-6f
#define IOU_EPS 1e-6f

constexpr int BLOCKS = 1792;   // 7 blocks/CU; 7168 waves; 100352 groups / 7168 = 14.0 exactly

__device__ __forceinline__ float iou_yolo(float a0, float a1, float a2, float a3,
                                          float b0, float b1, float b2, float b3) {
    float ax1 = a0 - a2 * 0.5f, ay1 = a1 - a3 * 0.5f;
    float ax2 = a0 + a2 * 0.5f, ay2 = a1 + a3 * 0.5f;
    float bx1 = b0 - b2 * 0.5f, by1 = b1 - b3 * 0.5f;
    float bx2 = b0 + b2 * 0.5f, by2 = b1 + b3 * 0.5f;
    float iw = fmaxf(fminf(ax2, bx2) - fmaxf(ax1, bx1), 0.0f);
    float ih = fmaxf(fminf(ay2, by2) - fmaxf(ay1, by1), 0.0f);
    float inter = iw * ih;
    float area_a = fabsf((ax2 - ax1) * (ay2 - ay1));
    float area_b = fabsf((bx2 - bx1) * (by2 - by1));
    return inter / (area_a + area_b - inter + IOU_EPS);
}

// Box/conf terms for one cell (class SSE handled separately, elementwise).
__device__ __forceinline__ float cell_terms(
    float b0, float b1, float b2, float b3, float t4,
    float p0, float p1, float p2, float p3, float p4,
    float p5, float p6, float p7, float p8, float p9) {
    float iou1 = iou_yolo(b0, b1, b2, b3, p0, p1, p2, p3);
    float iou2 = iou_yolo(b0, b1, b2, b3, p5, p6, p7, p8);
    bool use1 = iou1 > iou2;

    float bh0 = use1 ? p0 : p5;
    float bh1 = use1 ? p1 : p6;
    float bh2 = use1 ? p2 : p7;
    float bh3 = use1 ? p3 : p8;
    float conf_c = use1 ? p4 : p9;
    float conf_o = use1 ? p9 : p4;

    float dx = b0 - bh0, dy = b1 - bh1;
    float xy = LAMBDA_COORD * (dx * dx + dy * dy);

    float sw = sqrtf(b2) - sqrtf(fabsf(bh2 + WH_EPS));
    float sh = sqrtf(b3) - sqrtf(fabsf(bh3 + WH_EPS));
    float wh = LAMBDA_COORD * (sw * sw + sh * sh);

    float dc = t4 - conf_c;
    float obj_terms = xy + wh + dc * dc + LAMBDA_NOOBJ * conf_o * conf_o;

    float d4 = t4 - p4, d9 = t4 - p9;
    float noobj_terms = LAMBDA_NOOBJ * (d4 * d4 + d9 * d9);

    return (t4 == 1.0f) ? obj_terms : noobj_terms;
}

// m13-pattern streaming: each wave's lanes 0..59 load one CONTIGUOUS 960 B
// group (4 cell-pairs = 60 float4) per array per iteration. No LDS staging,
// no barriers in the hot loop -> continuous issue from 28 waves/CU.
// Cell assembly is done in-register with ds_bpermute (__shfl):
//   pair q (lanes b..b+14, b=15q), float idx within pair = 4u+j (u=lane-b):
//   cell A = floats 0..29, cell B = floats 30..59.
//   class SSE (floats 10..29 / 40..59) is elementwise per lane, masked by the
//   owning cell's objectness (2 broadcast shuffles), accumulated per-lane.
//   box/conf scalars gathered onto lane u==1 (cell A) and u==8 (cell B).
__global__ __launch_bounds__(256) void yolo_loss_kernel(
    const float4* __restrict__ tv, const float4* __restrict__ pv,
    float* __restrict__ out, int ngroups, float inv_batch) {
    const int lane = threadIdx.x & 63;
    const int widx = threadIdx.x >> 6;
    const int wave_id = blockIdx.x * 4 + widx;
    const int nwaves = gridDim.x * 4;

    const int u = lane % 15;        // float4 index within pair (lanes 60-63: junk, masked)
    const int bbase = lane - u;     // 15*q
    const bool active = lane < 60;

    // Per-lane class masks (compile-loop, runtime-constant per lane).
    float cm[4];
#pragma unroll
    for (int j = 0; j < 4; ++j) {
        int idx = 4 * u + j;
        bool isA = (idx >= 10 && idx < 30);
        bool isB = (idx >= 40);
        cm[j] = (isA || isB) ? 1.0f : 0.0f;
    }
    const bool sideA = (u <= 7);    // this lane's class elements belong to cell A

    float v = 0.0f;

    for (int g = wave_id; g < ngroups; g += nwaves) {
        float4 T = make_float4(0.f, 0.f, 0.f, 0.f);
        float4 P = make_float4(0.f, 0.f, 0.f, 0.f);
        if (active) {
            size_t base = (size_t)g * 60 + lane;
            T = tv[base];
            P = pv[base];
        }

        // Elementwise masked class SSE for this lane's 4 floats.
        float d0 = T.x - P.x, d1 = T.y - P.y, d2 = T.z - P.z, d3 = T.w - P.w;
        float s_cls = d0 * d0 * cm[0] + d1 * d1 * cm[1] +
                      d2 * d2 * cm[2] + d3 * d3 * cm[3];

        // Objectness of each cell: t4A = T.x of lane b+1; t4B = T.z of lane b+8.
        float t4A = __shfl(T.x, bbase + 1, 64);
        float t4B = __shfl(T.z, bbase + 8, 64);
        float objm = ((sideA ? t4A : t4B) == 1.0f) ? 1.0f : 0.0f;
        v += s_cls * objm;   // exactly the reference's cls term (obj cells only)

        // ---- gather cell A onto lane u==1 (owns t4=T.x, p4..p7=P.xyzw) ----
        float a_b0 = __shfl(T.x, bbase, 64);
        float a_b1 = __shfl(T.y, bbase, 64);
        float a_b2 = __shfl(T.z, bbase, 64);
        float a_b3 = __shfl(T.w, bbase, 64);
        float a_p0 = __shfl(P.x, bbase, 64);
        float a_p1 = __shfl(P.y, bbase, 64);
        float a_p2 = __shfl(P.z, bbase, 64);
        float a_p3 = __shfl(P.w, bbase, 64);
        float a_p8 = __shfl(P.x, bbase + 2, 64);
        float a_p9 = __shfl(P.y, bbase + 2, 64);

        // ---- gather cell B onto lane u==8 (owns b2=T.x,b3=T.y,t4=T.z, p2..p5=P.xyzw) ----
        float b_b0 = __shfl(T.z, bbase + 7, 64);
        float b_b1 = __shfl(T.w, bbase + 7, 64);
        float b_p0 = __shfl(P.z, bbase + 7, 64);
        float b_p1 = __shfl(P.w, bbase + 7, 64);
        float b_p6 = __shfl(P.x, bbase + 9, 64);
        float b_p7 = __shfl(P.y, bbase + 9, 64);
        float b_p8 = __shfl(P.z, bbase + 9, 64);
        float b_p9 = __shfl(P.w, bbase + 9, 64);

        // Compute on all lanes (garbage where not owner), select owners only.
        float cA = cell_terms(a_b0, a_b1, a_b2, a_b3, T.x,
                              a_p0, a_p1, a_p2, a_p3, P.x,
                              P.y, P.z, P.w, a_p8, a_p9);
        float cB = cell_terms(b_b0, b_b1, T.x, T.y, T.z,
                              b_p0, b_p1, P.x, P.y, P.z,
                              P.w, b_p6, b_p7, b_p8, b_p9);
        if (active && u == 1) v += cA;
        if (active && u == 8) v += cB;
    }

    // wave64 reduction -> per-wave LDS -> one atomic per block
#pragma unroll
    for (int off = 32; off > 0; off >>= 1)
        v += __shfl_down(v, off, 64);

    __shared__ float swave[4];
    if ((threadIdx.x & 63) == 0) swave[widx] = v;
    __syncthreads();
    if (threadIdx.x == 0) {
        float s = swave[0] + swave[1] + swave[2] + swave[3];
        atomicAdd(out, s * inv_batch);
    }
}

extern "C" void kernel_launch(void* const* d_in, const int* in_sizes, int n_in,
                              void* d_out, int out_size, void* d_ws, size_t ws_size,
                              hipStream_t stream) {
    const float* t = (const float*)d_in[0];  // y_trues
    const float* p = (const float*)d_in[1];  // y_preds
    float* out = (float*)d_out;

    const int total = in_sizes[0];        // 24,084,480
    const int cells = total / 30;         // 802,816
    const int ngroups = cells / 8;        // 100,352 groups of 4 cell-pairs (exact)
    const int batch = cells / 49;         // 16,384
    const float inv_batch = 1.0f / (float)batch;

    // d_out is poisoned (0xAA) before every replay — zero it on-stream.
    hipMemsetAsync(out, 0, sizeof(float), stream);

    yolo_loss_kernel<<<BLOCKS, 256, 0, stream>>>(
        (const float4*)t, (const float4*)p, out, ngroups, inv_batch);
}

// Round 7
// 207.646 us; speedup vs baseline: 1.1845x; 1.0253x over previous
//
#include <hip/hip_runtime.h>

#define LAMBDA_COORD 5.0f
#define LAMBDA_NOOBJ 0.5f
#define WH_EPS 1e-6f
#define IOU_EPS 1e-6f

constexpr int CHUNK_CELLS = 128;     // cells per chunk
constexpr int CHUNK_VEC4  = 960;     // float4 per array per chunk = 15,360 B
constexpr int NLOADS      = 15;      // 15 x (64 lanes x 16 B) = 15,360 B
constexpr int GRID        = 1280;    // 5 blocks/CU (LDS 30.7 KB -> 5 blocks/CU)

// IOU between box a (cx,cy,w,h) and b, matching _iou_yolo exactly.
__device__ __forceinline__ float iou_yolo(float a0, float a1, float a2, float a3,
                                          float b0, float b1, float b2, float b3) {
    float ax1 = a0 - a2 * 0.5f, ay1 = a1 - a3 * 0.5f;
    float ax2 = a0 + a2 * 0.5f, ay2 = a1 + a3 * 0.5f;
    float bx1 = b0 - b2 * 0.5f, by1 = b1 - b3 * 0.5f;
    float bx2 = b0 + b2 * 0.5f, by2 = b1 + b3 * 0.5f;
    float iw = fmaxf(fminf(ax2, bx2) - fmaxf(ax1, bx1), 0.0f);
    float ih = fmaxf(fminf(ay2, by2) - fmaxf(ay1, by1), 0.0f);
    float inter = iw * ih;
    float area_a = fabsf((ax2 - ax1) * (ay2 - ay1));
    float area_b = fabsf((bx2 - bx1) * (by2 - by1));
    return inter / (area_a + area_b - inter + IOU_EPS);
}

// Full loss for one cell; t/p point at 30 consecutive floats in LDS.
__device__ __forceinline__ float cell_loss(const float* t, const float* p) {
    const float b0 = t[0], b1 = t[1], b2 = t[2], b3 = t[3], t4 = t[4];

    float iou1 = iou_yolo(b0, b1, b2, b3, p[0], p[1], p[2], p[3]);
    float iou2 = iou_yolo(b0, b1, b2, b3, p[5], p[6], p[7], p[8]);
    bool use1 = iou1 > iou2;

    float bh0 = use1 ? p[0] : p[5];
    float bh1 = use1 ? p[1] : p[6];
    float bh2 = use1 ? p[2] : p[7];
    float bh3 = use1 ? p[3] : p[8];
    float conf_c = use1 ? p[4] : p[9];
    float conf_o = use1 ? p[9] : p[4];

    float dx = b0 - bh0, dy = b1 - bh1;
    float xy = LAMBDA_COORD * (dx * dx + dy * dy);

    float sw = sqrtf(b2) - sqrtf(fabsf(bh2 + WH_EPS));
    float sh = sqrtf(b3) - sqrtf(fabsf(bh3 + WH_EPS));
    float wh = LAMBDA_COORD * (sw * sw + sh * sh);

    float dc = t4 - conf_c;
    float obj_conf = dc * dc;
    float noobj_in_obj = LAMBDA_NOOBJ * conf_o * conf_o;

    float cls = 0.0f;
#pragma unroll
    for (int k = 10; k < 30; ++k) {
        float d = t[k] - p[k];
        cls += d * d;
    }

    float obj_terms = xy + wh + obj_conf + noobj_in_obj + cls;

    float d4 = t4 - p[4], d9 = t4 - p[9];
    float noobj_terms = LAMBDA_NOOBJ * (d4 * d4 + d9 * d9);

    return (t4 == 1.0f) ? obj_terms : noobj_terms;
}

// Fire-and-forget 16B global->LDS: wave-uniform LDS base, lane-contiguous global.
__device__ __forceinline__ void stage16(const float4* g_wave, float4* l_wave, int lane) {
    __builtin_amdgcn_global_load_lds(
        (const __attribute__((address_space(1))) void*)(g_wave + lane),
        (__attribute__((address_space(3))) void*)l_wave,
        16, 0, 0);
}

// WAVE-PRIVATE streaming: block == 1 wave. Each wave stages a contiguous
// 15,360 B chunk per array (30 fire-and-forget global_load_lds, no landing
// VGPRs -> compiler cannot batch-serialize; 30 KB in flight per wave), waits
// vmcnt(0) wave-locally (NO __syncthreads, no cross-wave convoy), computes
// 128 cells once each, repeats. 5 blocks/CU -> ~120 KB in flight per CU,
// ~12x the Little's-law requirement for 6.3 TB/s.
__global__ __launch_bounds__(64) void yolo_loss_kernel(
    const float4* __restrict__ tv, const float4* __restrict__ pv,
    float* __restrict__ out, int nchunks, float inv_batch) {
    __shared__ float4 st4[CHUNK_VEC4];
    __shared__ float4 sp4[CHUNK_VEC4];
    const float* st = (const float*)st4;
    const float* sp = (const float*)sp4;

    const int lane = threadIdx.x;   // 0..63, block is one wave

    float v = 0.0f;

    for (int chunk = blockIdx.x; chunk < nchunks; chunk += GRID) {
        const float4* tg = tv + (size_t)chunk * CHUNK_VEC4;
        const float4* pg = pv + (size_t)chunk * CHUNK_VEC4;

        // Issue all 30 DMAs back-to-back (vmcnt ops, no VGPR landing).
#pragma unroll
        for (int j = 0; j < NLOADS; ++j)
            stage16(tg + j * 64, st4 + j * 64, lane);
#pragma unroll
        for (int j = 0; j < NLOADS; ++j)
            stage16(pg + j * 64, sp4 + j * 64, lane);

        // Wave-local drain of the DMA queue before reading LDS.
        // imm encoding: vmcnt[3:0]=0, expcnt[6:4]=7, lgkmcnt[11:8]=0xF,
        // vmcnt[15:14]=0  -> 0x0F70 == s_waitcnt vmcnt(0).
        __builtin_amdgcn_s_waitcnt(0x0F70);

        // Compute: lane handles cells lane and lane+64 (adjacent-lane LDS
        // stride 30 words -> benign 2-way bank aliasing).
        v += cell_loss(st + lane * 30, sp + lane * 30);
        v += cell_loss(st + (lane + 64) * 30, sp + (lane + 64) * 30);

        // WAR guard: all LDS reads must complete before next iteration's DMA
        // overwrites the buffer. lgkmcnt(0) only -> imm 0xC07F.
        __builtin_amdgcn_s_waitcnt(0xC07F);
    }

    // wave64 reduction -> one atomic per block
#pragma unroll
    for (int off = 32; off > 0; off >>= 1)
        v += __shfl_down(v, off, 64);

    if (lane == 0) atomicAdd(out, v * inv_batch);
}

extern "C" void kernel_launch(void* const* d_in, const int* in_sizes, int n_in,
                              void* d_out, int out_size, void* d_ws, size_t ws_size,
                              hipStream_t stream) {
    const float* t = (const float*)d_in[0];  // y_trues
    const float* p = (const float*)d_in[1];  // y_preds
    float* out = (float*)d_out;

    const int total = in_sizes[0];            // 24,084,480
    const int cells = total / 30;             // 802,816
    const int nchunks = cells / CHUNK_CELLS;  // 6,272 (exact)
    const int batch = cells / 49;             // 16,384
    const float inv_batch = 1.0f / (float)batch;

    // d_out is poisoned (0xAA) before every replay — zero it on-stream.
    hipMemsetAsync(out, 0, sizeof(float), stream);

    yolo_loss_kernel<<<GRID, 64, 0, stream>>>(
        (const float4*)t, (const float4*)p, out, nchunks, inv_batch);
}

// Round 8
// 206.621 us; speedup vs baseline: 1.1903x; 1.0050x over previous
//
#include <hip/hip_runtime.h>

#define LAMBDA_COORD 5.0f
#define LAMBDA_NOOBJ 0.5f
#define WH_EPS 1e-6f
#define IOU_EPS 1e-6f

constexpr int CHUNK_CELLS = 64;                  // cells per chunk (1 per lane)
constexpr int CHUNK_VEC4  = CHUNK_CELLS * 30/4;  // 480 float4 = 7,680 B per array
constexpr int GRID        = 1280;                // 5 blocks/CU (LDS 30,720 B/block)

// IOU between box a (cx,cy,w,h) and b, matching _iou_yolo exactly.
__device__ __forceinline__ float iou_yolo(float a0, float a1, float a2, float a3,
                                          float b0, float b1, float b2, float b3) {
    float ax1 = a0 - a2 * 0.5f, ay1 = a1 - a3 * 0.5f;
    float ax2 = a0 + a2 * 0.5f, ay2 = a1 + a3 * 0.5f;
    float bx1 = b0 - b2 * 0.5f, by1 = b1 - b3 * 0.5f;
    float bx2 = b0 + b2 * 0.5f, by2 = b1 + b3 * 0.5f;
    float iw = fmaxf(fminf(ax2, bx2) - fmaxf(ax1, bx1), 0.0f);
    float ih = fmaxf(fminf(ay2, by2) - fmaxf(ay1, by1), 0.0f);
    float inter = iw * ih;
    float area_a = fabsf((ax2 - ax1) * (ay2 - ay1));
    float area_b = fabsf((bx2 - bx1) * (by2 - by1));
    return inter / (area_a + area_b - inter + IOU_EPS);
}

// Full loss for one cell; t/p point at 30 consecutive floats in LDS.
__device__ __forceinline__ float cell_loss(const float* t, const float* p) {
    const float b0 = t[0], b1 = t[1], b2 = t[2], b3 = t[3], t4 = t[4];

    float iou1 = iou_yolo(b0, b1, b2, b3, p[0], p[1], p[2], p[3]);
    float iou2 = iou_yolo(b0, b1, b2, b3, p[5], p[6], p[7], p[8]);
    bool use1 = iou1 > iou2;

    float bh0 = use1 ? p[0] : p[5];
    float bh1 = use1 ? p[1] : p[6];
    float bh2 = use1 ? p[2] : p[7];
    float bh3 = use1 ? p[3] : p[8];
    float conf_c = use1 ? p[4] : p[9];
    float conf_o = use1 ? p[9] : p[4];

    float dx = b0 - bh0, dy = b1 - bh1;
    float xy = LAMBDA_COORD * (dx * dx + dy * dy);

    float sw = sqrtf(b2) - sqrtf(fabsf(bh2 + WH_EPS));
    float sh = sqrtf(b3) - sqrtf(fabsf(bh3 + WH_EPS));
    float wh = LAMBDA_COORD * (sw * sw + sh * sh);

    float dc = t4 - conf_c;
    float obj_conf = dc * dc;
    float noobj_in_obj = LAMBDA_NOOBJ * conf_o * conf_o;

    float cls = 0.0f;
#pragma unroll
    for (int k = 10; k < 30; ++k) {
        float d = t[k] - p[k];
        cls += d * d;
    }

    float obj_terms = xy + wh + obj_conf + noobj_in_obj + cls;

    float d4 = t4 - p[4], d9 = t4 - p[9];
    float noobj_terms = LAMBDA_NOOBJ * (d4 * d4 + d9 * d9);

    return (t4 == 1.0f) ? obj_terms : noobj_terms;
}

// Fire-and-forget 16B global->LDS: wave-uniform LDS base, lane-contiguous global.
__device__ __forceinline__ void stage16(const float4* g_wave, float4* l_wave, int lane) {
    __builtin_amdgcn_global_load_lds(
        (const __attribute__((address_space(1))) void*)(g_wave + lane),
        (__attribute__((address_space(3))) void*)l_wave,
        16, 0, 0);
}

// Issue one array's chunk: 7 full-wave DMAs + 1 half-wave (480 = 7.5 * 64).
// Each instruction = +1 vmcnt regardless of exec mask -> 8 per array.
__device__ __forceinline__ void issue_array(const float4* g, float4* l, int lane) {
#pragma unroll
    for (int j = 0; j < 7; ++j)
        stage16(g + j * 64, l + j * 64, lane);
    if (lane < 32)
        stage16(g + 7 * 64, l + 7 * 64, lane);
}

// SOFTWARE-PIPELINED wave-private streaming (AITER-style vmcnt(N), never 0
// in steady state). Block = 1 wave, double-buffered LDS, no barriers:
//   issue chunk k+1 (16 DMAs; 32 outstanding) -> s_waitcnt vmcnt(16)
//   (chunk k ready, chunk k+1 STAYS IN FLIGHT through compute) ->
//   compute 64 cells -> lgkmcnt(0) WAR guard -> swap parity.
// The memory pipe never drains: ~15 KB/wave * 5 waves/CU sustained.
__global__ __launch_bounds__(64) void yolo_loss_kernel(
    const float4* __restrict__ tv, const float4* __restrict__ pv,
    float* __restrict__ out, int nchunks, float inv_batch) {
    __shared__ float4 sbuf[2][2][CHUNK_VEC4];   // [parity][t/p][...] = 30,720 B

    const int lane = threadIdx.x;   // block is one wave

    float v = 0.0f;
    int g = blockIdx.x;
    int parity = 0;

    if (g < nchunks) {   // prologue: prefetch first chunk into buffer 0
        issue_array(tv + (size_t)g * CHUNK_VEC4, sbuf[0][0], lane);
        issue_array(pv + (size_t)g * CHUNK_VEC4, sbuf[0][1], lane);
    }

    while (g < nchunks) {
        const int gn = g + GRID;
        const bool have_next = gn < nchunks;
        if (have_next) {   // prefetch next chunk into other buffer
            issue_array(tv + (size_t)gn * CHUNK_VEC4, sbuf[1 - parity][0], lane);
            issue_array(pv + (size_t)gn * CHUNK_VEC4, sbuf[1 - parity][1], lane);
            // 32 outstanding; wait until only the 16 newest remain.
            __builtin_amdgcn_s_waitcnt(0x4F70);   // vmcnt(16)
        } else {
            __builtin_amdgcn_s_waitcnt(0x0F70);   // vmcnt(0)
        }

        const float* st = (const float*)sbuf[parity][0];
        const float* sp = (const float*)sbuf[parity][1];
        v += cell_loss(st + lane * 30, sp + lane * 30);

        // WAR guard: this buffer's ds_reads must retire before it is
        // overwritten by the DMA issued two iterations from now.
        __builtin_amdgcn_s_waitcnt(0xC07F);       // lgkmcnt(0)

        parity = 1 - parity;
        g = gn;
    }

    // wave64 reduction -> one atomic per block
#pragma unroll
    for (int off = 32; off > 0; off >>= 1)
        v += __shfl_down(v, off, 64);

    if (lane == 0) atomicAdd(out, v * inv_batch);
}

extern "C" void kernel_launch(void* const* d_in, const int* in_sizes, int n_in,
                              void* d_out, int out_size, void* d_ws, size_t ws_size,
                              hipStream_t stream) {
    const float* t = (const float*)d_in[0];  // y_trues
    const float* p = (const float*)d_in[1];  // y_preds
    float* out = (float*)d_out;

    const int total = in_sizes[0];            // 24,084,480
    const int cells = total / 30;             // 802,816
    const int nchunks = cells / CHUNK_CELLS;  // 12,544 (exact)
    const int batch = cells / 49;             // 16,384
    const float inv_batch = 1.0f / (float)batch;

    // d_out is poisoned (0xAA) before every replay — zero it on-stream.
    hipMemsetAsync(out, 0, sizeof(float), stream);

    yolo_loss_kernel<<<GRID, 64, 0, stream>>>(
        (const float4*)t, (const float4*)p, out, nchunks, inv_batch);
}